// Round 1
// 74.918 us; speedup vs baseline: 1.0578x; 1.0578x over previous
//
#include <hip/hip_runtime.h>

#define NSEG 128
#define SSTEPS 32
#define TDIM 32
#define NG 8               // banked accumulator copies = blockDim/32
#define DROWS 37           // rows base..base+2, base in [0,34]; s>=32 junk
#define SPB 8              // splits per segment
#define CSTR (DROWS * TDIM)   // 1184 floats per banked copy

// ---------------- Kernel: per-(segment,split) tiles, fused epilogue ---------
// Difference-domain accumulation: per (node,t), d/ds of the sigmoid step
// profile has exactly 3 nonzero entries at consecutive rows summing to 1.
// Thread (g=tid>>5, t=tid&31) exclusively owns d[g][*][t] -> plain RMW.
// Epilogue: fold banked copies, prefix over s, atomicAdd into out directly.
// R1 changes vs 78.5us baseline:
//   * f32 divisions -> __builtin_amdgcn_rcpf (v_rcp_f32). Default hipcc
//     emits the full IEEE div_scale/div_fmas/div_fixup sequence (~10-15
//     instr each, 2 per node) -- ~30% of inner-loop VALU.
//   * software-pipelined x loads: issue next node's 3 loads before the
//     exp/rcp/LDS-RMW tail of the current node (hides L1/L2 latency).
//   * u = fmaf(nh, inv_step, -lin0*inv_step) (one fewer VALU op).
__global__ __launch_bounds__(256) void ect_kernel(
    const float* __restrict__ x,       // [N,3]
    const int*   __restrict__ idx,     // [N] int32 or int64 (N even; detected)
    const float* __restrict__ v,       // [3,32]
    const float* __restrict__ lin,     // [32]
    const int*   __restrict__ scale_p, // [1]
    float*       __restrict__ out,     // [NSEG,32,32], pre-zeroed
    int N)
{
    __shared__ float d[NG][DROWS][TDIM];   // 37.9 KB
    __shared__ int s_bounds[2];

    const int tid = threadIdx.x;
    const unsigned bx = blockIdx.x;
    const int b = bx >> 3;            // segment
    const int j = bx & (SPB - 1);     // split

    // ---- wave-parallel segment-boundary search (wave 0) ----
    // halves: lanes 0-31 -> target b, lanes 32-63 -> target b+1
    if (tid < 64) {
        const int L = tid & 31;
        const int h = tid >> 5;
        const int target = b + h;
        const int g0 = (int)(((long long)target * N) >> 7);  // *N/128 guess

        const int hi_last = idx[N - 1];          // ==0 iff int64 (N even)
        int p1 = g0 - 1024 + 64 * L;
        int pc1 = min(max(p1, 0), N - 1);
        int val32 = idx[pc1];
        const bool is64 = (hi_last == 0);
        int val = is64 ? idx[2 * pc1] : val32;

        bool pred1 = (p1 < 0) ? true : ((p1 >= N) ? false : (val < target));
        unsigned long long m1 = __ballot(pred1);
        unsigned hm1 = (unsigned)(m1 >> (h * 32));

        if (hm1 == 0u || hm1 == 0xFFFFFFFFu) {
            if (L == 0) {                       // rare fallback: serial search
                int lo = 0, hi = N;
                while (lo < hi) {
                    int mid = (lo + hi) >> 1;
                    int vv = is64 ? idx[2 * mid] : idx[mid];
                    if (vv < target) lo = mid + 1; else hi = mid;
                }
                s_bounds[h] = lo;
            }
        } else {
            const int A = g0 - 1024 + 64 * (31 - __builtin_clz(hm1));
            int p2 = A + 1 + 2 * L;
            int pc2 = min(max(p2, 0), N - 1);
            int v2 = is64 ? idx[2 * pc2] : idx[pc2];
            bool pred2 = (p2 < 0) ? true : ((p2 >= N) ? false : (v2 < target));
            unsigned long long m2 = __ballot(pred2);
            unsigned hm2 = (unsigned)(m2 >> (h * 32));
            const int B = hm2 ? (A + 1 + 2 * (31 - __builtin_clz(hm2))) : A;
            int p3 = B + 1;
            int pc3 = min(p3, N - 1);
            int v3 = is64 ? idx[2 * pc3] : idx[pc3];
            bool pred3 = (p3 >= N) ? false : (v3 < target);
            if (L == 0) s_bounds[h] = pred3 ? (B + 2) : (B + 1);
        }
    }
    // zero-init banked accumulators (float4)
    {
        float4* dz = (float4*)d;
        for (int i = tid; i < NG * CSTR / 4; i += 256)
            dz[i] = make_float4(0.f, 0.f, 0.f, 0.f);
    }

    const float lin0 = lin[0];
    const float step = lin[1] - lin0;
    const float inv_step = 1.0f / step;
    const float negl0 = -lin0 * inv_step;
    const float scale = (float)scale_p[0];
    const float zstep = scale * step;          // ~35.48
    const float C = __expf(zstep);             // e^{zstep}, finite

    const int t = tid & 31;
    const int g = tid >> 5;
    const float v0 = v[t], v1 = v[TDIM + t], v2 = v[2 * TDIM + t];
    float* dg = &d[g][0][t];                   // row stride = 32 floats

    __syncthreads();

    const int start = s_bounds[0], end = s_bounds[1];
    const int cnt = end - start;
    const int chunk = (cnt + SPB - 1) / SPB;
    const int k0 = start + j * chunk;
    const int k1 = min(k0 + chunk, end);

    // software-pipelined main loop: prefetch next node's x while finishing
    // the current node's exp/rcp/LDS-RMW tail.
    int k = k0 + g;
    if (k < k1) {
        float cx0 = x[k * 3 + 0];
        float cx1 = x[k * 3 + 1];
        float cx2 = x[k * 3 + 2];
        while (k < k1) {
            const int kn = k + NG;
            const int kc = min(kn, k1 - 1);        // safe prefetch address
            const float n0 = x[kc * 3 + 0];
            const float n1 = x[kc * 3 + 1];
            const float n2 = x[kc * 3 + 2];

            const float nh = fmaf(cx0, v0, fmaf(cx1, v1, cx2 * v2));

            float u = fmaf(nh, inv_step, negl0);
            u = fminf(fmaxf(u, -2.0f), 34.0f);
            const float sf = floorf(u);
            const int s_lo = (int)sf;

            // single exp serves both bracketing sigmoids; fast v_rcp_f32
            // instead of IEEE f32 division (tolerance has huge headroom)
            const float E = __expf((sf - u) * zstep);     // e^{z0} in (0,1]
            const float rc = __builtin_amdgcn_rcpf(1.0f + E);
            const float sig0  = E * rc;
            const float sig1c = __builtin_amdgcn_rcpf(fmaf(E, C, 1.0f));

            float w0 = sig0;
            float w1 = 1.0f - sig0 - sig1c;
            float w2 = sig1c;                             // sums to 1

            // left clamp by weight shift -> rows always consecutive
            if (s_lo < 0) {
                if (s_lo == -1) { w0 = w0 + w1; w1 = w2; w2 = 0.f; }
                else            { w0 = 1.0f;    w1 = 0.f; w2 = 0.f; }
            }
            const int base = max(s_lo, 0);                // 0..34

            float* p = dg + base * 32;
            const float a0 = p[0];                        // ds_read2 + ds_read
            const float a1 = p[32];
            const float a2 = p[64];
            p[0]  = a0 + w0;                              // ds_write2 + ds_write
            p[32] = a1 + w1;
            p[64] = a2 + w2;

            cx0 = n0; cx1 = n1; cx2 = n2;
            k = kn;
        }
    }
    __syncthreads();

    // fold NG banked copies into copy 0, rows 0..31 (float4 b128 reads)
    {
        const float* basep = (const float*)d;
        float4 sum = make_float4(0.f, 0.f, 0.f, 0.f);
        #pragma unroll
        for (int gg = 0; gg < NG; ++gg) {
            const float4 vq = ((const float4*)(basep + gg * CSTR))[tid];
            sum.x += vq.x; sum.y += vq.y; sum.z += vq.z; sum.w += vq.w;
        }
        ((float4*)d)[tid] = sum;
    }
    __syncthreads();

    // prefix-sum diffs over s per t (32 threads), back into LDS
    if (tid < TDIM) {
        float* df = (float*)d;
        float run = 0.f;
        #pragma unroll
        for (int s = 0; s < SSTEPS; ++s) {
            run += df[s * 32 + tid];
            df[s * 32 + tid] = run;
        }
    }
    __syncthreads();

    // fused reduction: atomicAdd tile into out (coalesced, 4 cells/thread)
    {
        const float* df = (const float*)d;
        float* ob = out + (size_t)b * (SSTEPS * TDIM);
        #pragma unroll
        for (int q = 0; q < 4; ++q)
            atomicAdd(&ob[q * 256 + tid], df[q * 256 + tid]);
    }
}

extern "C" void kernel_launch(void* const* d_in, const int* in_sizes, int n_in,
                              void* d_out, int out_size, void* d_ws, size_t ws_size,
                              hipStream_t stream) {
    const float* x     = (const float*)d_in[0];
    const int*   index = (const int*)d_in[1];
    const float* v     = (const float*)d_in[2];
    const float* lin   = (const float*)d_in[3];
    const int*   scale = (const int*)d_in[4];
    float* out = (float*)d_out;
    const int N = in_sizes[0] / 3;   // x is [N,3]

    hipMemsetAsync(d_out, 0, (size_t)out_size * sizeof(float), stream);
    ect_kernel<<<NSEG * SPB, 256, 0, stream>>>(x, index, v, lin, scale, out, N);
}

// Round 2
// 73.286 us; speedup vs baseline: 1.0813x; 1.0223x over previous
//
#include <hip/hip_runtime.h>

#define NSEG 128
#define SSTEPS 32
#define TDIM 32
#define NG 8               // banked accumulator copies = blockDim/32
#define DROWS 37           // rows base..base+2, base in [0,34]; s>=32 junk
#define SPB 8              // splits per segment
#define CSTR (DROWS * TDIM)   // 1184 floats per banked copy
#define UNR 4              // software-pipeline batch width (nodes per thread)

// ---------------- Kernel: per-(segment,split) tiles, fused epilogue ---------
// Difference-domain accumulation: per (node,t), d/ds of the sigmoid step
// profile has exactly 3 nonzero entries at consecutive rows summing to 1.
// Thread (g=tid>>5, t=tid&31) exclusively owns d[g][*][t] -> plain RMW.
// Epilogue: fold banked copies, prefix over s, atomicAdd into out directly.
// R2 changes vs 74.9us:
//   * 4-wide batched software pipeline: load next 4 nodes' x while
//     processing current 4. Old 1-deep prefetch gave only ~110 cyc of
//     cover; L2/HBM misses are 200-900 cyc and occupancy is LDS-capped
//     at 4 waves/SIMD, so the wave stalled in vmcnt almost every iter.
//     4x MLP + ~440 cyc prefetch distance + 4 independent exp/LDS chains.
__global__ __launch_bounds__(256) void ect_kernel(
    const float* __restrict__ x,       // [N,3]
    const int*   __restrict__ idx,     // [N] int32 or int64 (N even; detected)
    const float* __restrict__ v,       // [3,32]
    const float* __restrict__ lin,     // [32]
    const int*   __restrict__ scale_p, // [1]
    float*       __restrict__ out,     // [NSEG,32,32], pre-zeroed
    int N)
{
    __shared__ float d[NG][DROWS][TDIM];   // 37.9 KB
    __shared__ int s_bounds[2];

    const int tid = threadIdx.x;
    const unsigned bx = blockIdx.x;
    const int b = bx >> 3;            // segment
    const int j = bx & (SPB - 1);     // split

    // ---- wave-parallel segment-boundary search (wave 0) ----
    // halves: lanes 0-31 -> target b, lanes 32-63 -> target b+1
    if (tid < 64) {
        const int L = tid & 31;
        const int h = tid >> 5;
        const int target = b + h;
        const int g0 = (int)(((long long)target * N) >> 7);  // *N/128 guess

        const int hi_last = idx[N - 1];          // ==0 iff int64 (N even)
        int p1 = g0 - 1024 + 64 * L;
        int pc1 = min(max(p1, 0), N - 1);
        int val32 = idx[pc1];
        const bool is64 = (hi_last == 0);
        int val = is64 ? idx[2 * pc1] : val32;

        bool pred1 = (p1 < 0) ? true : ((p1 >= N) ? false : (val < target));
        unsigned long long m1 = __ballot(pred1);
        unsigned hm1 = (unsigned)(m1 >> (h * 32));

        if (hm1 == 0u || hm1 == 0xFFFFFFFFu) {
            if (L == 0) {                       // rare fallback: serial search
                int lo = 0, hi = N;
                while (lo < hi) {
                    int mid = (lo + hi) >> 1;
                    int vv = is64 ? idx[2 * mid] : idx[mid];
                    if (vv < target) lo = mid + 1; else hi = mid;
                }
                s_bounds[h] = lo;
            }
        } else {
            const int A = g0 - 1024 + 64 * (31 - __builtin_clz(hm1));
            int p2 = A + 1 + 2 * L;
            int pc2 = min(max(p2, 0), N - 1);
            int v2 = is64 ? idx[2 * pc2] : idx[pc2];
            bool pred2 = (p2 < 0) ? true : ((p2 >= N) ? false : (v2 < target));
            unsigned long long m2 = __ballot(pred2);
            unsigned hm2 = (unsigned)(m2 >> (h * 32));
            const int B = hm2 ? (A + 1 + 2 * (31 - __builtin_clz(hm2))) : A;
            int p3 = B + 1;
            int pc3 = min(p3, N - 1);
            int v3 = is64 ? idx[2 * pc3] : idx[pc3];
            bool pred3 = (p3 >= N) ? false : (v3 < target);
            if (L == 0) s_bounds[h] = pred3 ? (B + 2) : (B + 1);
        }
    }
    // zero-init banked accumulators (float4)
    {
        float4* dz = (float4*)d;
        for (int i = tid; i < NG * CSTR / 4; i += 256)
            dz[i] = make_float4(0.f, 0.f, 0.f, 0.f);
    }

    const float lin0 = lin[0];
    const float step = lin[1] - lin0;
    const float inv_step = 1.0f / step;
    const float negl0 = -lin0 * inv_step;
    const float scale = (float)scale_p[0];
    const float zstep = scale * step;          // ~35.48
    const float C = __expf(zstep);             // e^{zstep}, finite

    const int t = tid & 31;
    const int g = tid >> 5;
    const float v0 = v[t], v1 = v[TDIM + t], v2 = v[2 * TDIM + t];
    float* dg = &d[g][0][t];                   // row stride = 32 floats

    __syncthreads();

    const int start = s_bounds[0], end = s_bounds[1];
    const int cnt = end - start;
    const int chunk = (cnt + SPB - 1) / SPB;
    const int k0 = start + j * chunk;
    const int k1 = min(k0 + chunk, end);

    // one node's full computation + banked-LDS RMW
    auto process = [&](float x0, float x1, float x2) {
        const float nh = fmaf(x0, v0, fmaf(x1, v1, x2 * v2));

        float u = fmaf(nh, inv_step, negl0);
        u = fminf(fmaxf(u, -2.0f), 34.0f);
        const float sf = floorf(u);
        const int s_lo = (int)sf;

        // single exp serves both bracketing sigmoids; fast v_rcp_f32
        const float E = __expf((sf - u) * zstep);     // e^{z0} in (0,1]
        const float rc = __builtin_amdgcn_rcpf(1.0f + E);
        const float sig0  = E * rc;
        const float sig1c = __builtin_amdgcn_rcpf(fmaf(E, C, 1.0f));

        float w0 = sig0;
        float w1 = 1.0f - sig0 - sig1c;
        float w2 = sig1c;                             // sums to 1

        // left clamp by weight shift -> rows always consecutive
        if (s_lo < 0) {
            if (s_lo == -1) { w0 = w0 + w1; w1 = w2; w2 = 0.f; }
            else            { w0 = 1.0f;    w1 = 0.f; w2 = 0.f; }
        }
        const int base = max(s_lo, 0);                // 0..34

        float* p = dg + base * 32;
        const float a0 = p[0];                        // ds_read2 + ds_read
        const float a1 = p[32];
        const float a2 = p[64];
        p[0]  = a0 + w0;                              // ds_write2 + ds_write
        p[32] = a1 + w1;
        p[64] = a2 + w2;
    };

    // ---- 4-wide batched software pipeline over this thread's nodes ----
    {
        int k = k0 + g;
        const int nit = (k < k1) ? ((k1 - k) + NG - 1) / NG : 0;
        const int nb = nit / UNR;                 // full batches of 4

        float cx[UNR][3];
        if (nb > 0) {
            #pragma unroll
            for (int i = 0; i < UNR; ++i) {
                const int kk = k + i * NG;
                cx[i][0] = x[kk * 3 + 0];
                cx[i][1] = x[kk * 3 + 1];
                cx[i][2] = x[kk * 3 + 2];
            }
        }
        for (int bi = 0; bi < nb; ++bi) {
            const int knext = k + UNR * NG;
            const bool more = (bi + 1 < nb);
            float nx[UNR][3];
            // issue next batch's loads (safe dummy addr on last batch)
            #pragma unroll
            for (int i = 0; i < UNR; ++i) {
                const int kk = more ? (knext + i * NG) : k;
                nx[i][0] = x[kk * 3 + 0];
                nx[i][1] = x[kk * 3 + 1];
                nx[i][2] = x[kk * 3 + 2];
            }
            // process current batch (4 independent chains)
            #pragma unroll
            for (int i = 0; i < UNR; ++i)
                process(cx[i][0], cx[i][1], cx[i][2]);
            #pragma unroll
            for (int i = 0; i < UNR; ++i) {
                cx[i][0] = nx[i][0]; cx[i][1] = nx[i][1]; cx[i][2] = nx[i][2];
            }
            k = knext;
        }
        // tail (< UNR iterations)
        for (k = k0 + g + nb * UNR * NG; k < k1; k += NG)
            process(x[k * 3 + 0], x[k * 3 + 1], x[k * 3 + 2]);
    }
    __syncthreads();

    // fold NG banked copies into copy 0, rows 0..31 (float4 b128 reads)
    {
        const float* basep = (const float*)d;
        float4 sum = make_float4(0.f, 0.f, 0.f, 0.f);
        #pragma unroll
        for (int gg = 0; gg < NG; ++gg) {
            const float4 vq = ((const float4*)(basep + gg * CSTR))[tid];
            sum.x += vq.x; sum.y += vq.y; sum.z += vq.z; sum.w += vq.w;
        }
        ((float4*)d)[tid] = sum;
    }
    __syncthreads();

    // prefix-sum diffs over s per t (32 threads), back into LDS
    if (tid < TDIM) {
        float* df = (float*)d;
        float run = 0.f;
        #pragma unroll
        for (int s = 0; s < SSTEPS; ++s) {
            run += df[s * 32 + tid];
            df[s * 32 + tid] = run;
        }
    }
    __syncthreads();

    // fused reduction: atomicAdd tile into out (coalesced, 4 cells/thread)
    {
        const float* df = (const float*)d;
        float* ob = out + (size_t)b * (SSTEPS * TDIM);
        #pragma unroll
        for (int q = 0; q < 4; ++q)
            atomicAdd(&ob[q * 256 + tid], df[q * 256 + tid]);
    }
}

extern "C" void kernel_launch(void* const* d_in, const int* in_sizes, int n_in,
                              void* d_out, int out_size, void* d_ws, size_t ws_size,
                              hipStream_t stream) {
    const float* x     = (const float*)d_in[0];
    const int*   index = (const int*)d_in[1];
    const float* v     = (const float*)d_in[2];
    const float* lin   = (const float*)d_in[3];
    const int*   scale = (const int*)d_in[4];
    float* out = (float*)d_out;
    const int N = in_sizes[0] / 3;   // x is [N,3]

    hipMemsetAsync(d_out, 0, (size_t)out_size * sizeof(float), stream);
    ect_kernel<<<NSEG * SPB, 256, 0, stream>>>(x, index, v, lin, scale, out, N);
}